// Round 1
// baseline (178.643 us; speedup 1.0000x reference)
//
#include <hip/hip_runtime.h>
#include <math.h>

// ---------------------------------------------------------------------------
// EntRNN: x = tanh(inputs @ W_in^T + b_in); f = sigmoid(inputs @ W_f^T + b_f
//          + mask*1e4); h_t = f*x + (1-f)*h_{t-1} scanned over T.
// B=8, T=4096, D_IN=D_OUT=256. Output fp32 (B,T,256).
//
// Plan: K0 convert W->f16 | K1 barrier-free MFMA GEMM + activation epilogue
//       writing x,f to ws | K2a/K2b/K2c chunked (C=64) linear scan, fully
//       coalesced in [t][d] layout.
// ---------------------------------------------------------------------------

typedef _Float16 f16x8 __attribute__((ext_vector_type(8)));
typedef _Float16 f16x4_t __attribute__((ext_vector_type(4)));
typedef float f32x4 __attribute__((ext_vector_type(4)));

constexpr int B_ = 8, T_ = 4096, D_ = 256, K_ = 256;
constexpr int M_ = B_ * T_;          // 32768 rows
constexpr int CHUNK = 64;            // scan chunk length
constexpr int NCH = T_ / CHUNK;      // 64 chunks per sequence

// ---- storage helpers (fp32 or bf16 intermediates, picked by ws_size) ------
__device__ __forceinline__ float ldst(const float* p, size_t i) { return p[i]; }
__device__ __forceinline__ float ldst(const __bf16* p, size_t i) { return (float)p[i]; }
__device__ __forceinline__ void stst(float* p, size_t i, float v) { p[i] = v; }
__device__ __forceinline__ void stst(__bf16* p, size_t i, float v) { p[i] = (__bf16)v; }

// ---- K0: convert both weight matrices fp32 -> f16, concatenated [2][256][256]
__global__ __launch_bounds__(256) void wconv(const float* __restrict__ Win,
                                             const float* __restrict__ Wf,
                                             _Float16* __restrict__ Wh) {
  int i = (blockIdx.x * 256 + threadIdx.x) * 4;   // 128 blocks -> 131072 elems
  const float* src = (i < 65536) ? (Win + i) : (Wf + (i - 65536));
  f32x4 v = *(const f32x4*)src;
  f16x4_t o = { (_Float16)v[0], (_Float16)v[1], (_Float16)v[2], (_Float16)v[3] };
  *(f16x4_t*)(Wh + i) = o;
}

// ---- K1: GEMM + activation. grid = 256 m-blocks x 2 matrix-halves ---------
// block tile: 128 rows x 256 cols of one weight matrix; 4 waves (2m x 2n),
// wave tile 64m x 128n = 4 x 8 MFMA 16x16 tiles. No LDS, no barriers.
template <typename ST>
__global__ __launch_bounds__(256, 2) void gemm_act(
    const float* __restrict__ A, const _Float16* __restrict__ W,
    const float* __restrict__ bin, const float* __restrict__ bfv,
    const float* __restrict__ mask, ST* __restrict__ wsx, ST* __restrict__ wsf) {
  const int mb = blockIdx.x >> 1, hf = blockIdx.x & 1;
  const int tid = threadIdx.x;
  const int w = tid >> 6, lane = tid & 63;
  const int quad = lane >> 4, l16 = lane & 15;
  const int mwb = (w >> 1) * 64, nwb = (w & 1) * 128;
  const int row0 = mb * 128 + mwb;
  const _Float16* Wp = W + ((size_t)hf << 16);

  f32x4 acc[4][8];
#pragma unroll
  for (int i = 0; i < 4; ++i)
#pragma unroll
    for (int j = 0; j < 8; ++j) acc[i][j] = (f32x4){0.f, 0.f, 0.f, 0.f};

  for (int kk = 0; kk < 8; ++kk) {
    const int k0 = kk * 32 + quad * 8;
    f16x8 afr[4];
#pragma unroll
    for (int mt = 0; mt < 4; ++mt) {
      // A fragment: A[m = lane&15][k = quad*8 + j], fp32 -> f16
      const float* p = A + (size_t)(row0 + mt * 16 + l16) * K_ + k0;
      f32x4 lo = *(const f32x4*)p;
      f32x4 hi = *(const f32x4*)(p + 4);
      f16x8 t;
      t[0] = (_Float16)lo[0]; t[1] = (_Float16)lo[1];
      t[2] = (_Float16)lo[2]; t[3] = (_Float16)lo[3];
      t[4] = (_Float16)hi[0]; t[5] = (_Float16)hi[1];
      t[6] = (_Float16)hi[2]; t[7] = (_Float16)hi[3];
      afr[mt] = t;
    }
    f16x8 bfr[8];
#pragma unroll
    for (int nt = 0; nt < 8; ++nt)  // B fragment: W[n = lane&15][k contiguous]
      bfr[nt] = *(const f16x8*)(Wp + (size_t)(nwb + nt * 16 + l16) * K_ + k0);
#pragma unroll
    for (int mt = 0; mt < 4; ++mt)
#pragma unroll
      for (int nt = 0; nt < 8; ++nt)
        acc[mt][nt] = __builtin_amdgcn_mfma_f32_16x16x32_f16(afr[mt], bfr[nt],
                                                             acc[mt][nt], 0, 0, 0);
  }

  // epilogue: C/D layout col = lane&15, row = quad*4 + r
  float bias[8];
#pragma unroll
  for (int nt = 0; nt < 8; ++nt) {
    const int col = nwb + nt * 16 + l16;
    bias[nt] = hf ? bfv[col] : bin[col];
  }
#pragma unroll
  for (int mt = 0; mt < 4; ++mt) {
#pragma unroll
    for (int r = 0; r < 4; ++r) {
      const int row = row0 + mt * 16 + quad * 4 + r;
      const float madd = hf ? 10000.f * mask[row] : 0.f;
#pragma unroll
      for (int nt = 0; nt < 8; ++nt) {
        const int col = nwb + nt * 16 + l16;
        const float z = acc[mt][nt][r] + bias[nt] + madd;
        if (hf)
          stst(wsf, (size_t)row * D_ + col, 1.f / (1.f + expf(-z)));
        else
          stst(wsx, (size_t)row * D_ + col, tanhf(z));
      }
    }
  }
}

// ---- K2a: per-chunk summaries (A = prod(1-f), h with h_start = 0) ---------
template <typename ST>
__global__ __launch_bounds__(256) void scan_a(const ST* __restrict__ wsx,
                                              const ST* __restrict__ wsf,
                                              float* __restrict__ Ap,
                                              float* __restrict__ Hp) {
  const int d = threadIdx.x;
  const int b = blockIdx.x >> 6, c = blockIdx.x & 63;
  const size_t base = ((size_t)b * T_ + (size_t)c * CHUNK) * D_ + d;
  float Aacc = 1.f, h = 0.f;
#pragma unroll 8
  for (int i = 0; i < CHUNK; ++i) {
    const float x = ldst(wsx, base + (size_t)i * D_);
    const float f = ldst(wsf, base + (size_t)i * D_);
    const float a = 1.f - f;
    h = f * x + a * h;
    Aacc *= a;
  }
  Ap[(size_t)blockIdx.x * D_ + d] = Aacc;
  Hp[(size_t)blockIdx.x * D_ + d] = h;
}

// ---- K2b: serial combine of 64 chunk summaries per (b,d) ------------------
__global__ __launch_bounds__(256) void scan_b(const float* __restrict__ Ap,
                                              const float* __restrict__ Hp,
                                              float* __restrict__ hs) {
  const int d = threadIdx.x, b = blockIdx.x;
  float h = 0.f;
#pragma unroll 8
  for (int c = 0; c < NCH; ++c) {
    const size_t idx = ((size_t)b * NCH + c) * D_ + d;
    hs[idx] = h;                       // carry INTO chunk c
    h = Hp[idx] + Ap[idx] * h;
  }
}

// ---- K2c: replay chunks with true h_start, write output -------------------
template <typename ST>
__global__ __launch_bounds__(256) void scan_c(const ST* __restrict__ wsx,
                                              const ST* __restrict__ wsf,
                                              const float* __restrict__ hs,
                                              float* __restrict__ out) {
  const int d = threadIdx.x;
  const int b = blockIdx.x >> 6, c = blockIdx.x & 63;
  float h = hs[(size_t)blockIdx.x * D_ + d];
  const size_t base = ((size_t)b * T_ + (size_t)c * CHUNK) * D_ + d;
#pragma unroll 8
  for (int i = 0; i < CHUNK; ++i) {
    const float x = ldst(wsx, base + (size_t)i * D_);
    const float f = ldst(wsf, base + (size_t)i * D_);
    h = f * x + (1.f - f) * h;
    out[base + (size_t)i * D_] = h;
  }
}

// ---------------------------------------------------------------------------
extern "C" void kernel_launch(void* const* d_in, const int* in_sizes, int n_in,
                              void* d_out, int out_size, void* d_ws, size_t ws_size,
                              hipStream_t stream) {
  const float* inputs = (const float*)d_in[0];
  const float* mask   = (const float*)d_in[1];
  const float* W_in   = (const float*)d_in[2];
  const float* b_in   = (const float*)d_in[3];
  const float* W_f    = (const float*)d_in[4];
  const float* b_f    = (const float*)d_in[5];
  float* out = (float*)d_out;
  char* ws = (char*)d_ws;

  constexpr size_t XF32 = (size_t)M_ * D_ * sizeof(float);   // 32 MiB
  constexpr size_t XF16 = (size_t)M_ * D_ * 2;               // 16 MiB
  constexpr size_t WSZ  = (size_t)2 * 256 * 256 * 2;         // 256 KiB
  constexpr size_t SUM  = (size_t)B_ * NCH * D_ * sizeof(float); // 512 KiB

  const bool use32 = ws_size >= 2 * XF32 + WSZ + 3 * SUM;

  if (use32) {
    float* wsx = (float*)ws;
    float* wsf = (float*)(ws + XF32);
    _Float16* Wh = (_Float16*)(ws + 2 * XF32);
    float* Ap = (float*)(ws + 2 * XF32 + WSZ);
    float* Hp = Ap + SUM / sizeof(float);
    float* Hs = Hp + SUM / sizeof(float);

    wconv<<<128, 256, 0, stream>>>(W_in, W_f, Wh);
    gemm_act<float><<<512, 256, 0, stream>>>(inputs, Wh, b_in, b_f, mask, wsx, wsf);
    scan_a<float><<<512, 256, 0, stream>>>(wsx, wsf, Ap, Hp);
    scan_b<<<8, 256, 0, stream>>>(Ap, Hp, Hs);
    scan_c<float><<<512, 256, 0, stream>>>(wsx, wsf, Hs, out);
  } else {
    __bf16* wsx = (__bf16*)ws;
    __bf16* wsf = (__bf16*)(ws + XF16);
    _Float16* Wh = (_Float16*)(ws + 2 * XF16);
    float* Ap = (float*)(ws + 2 * XF16 + WSZ);
    float* Hp = Ap + SUM / sizeof(float);
    float* Hs = Hp + SUM / sizeof(float);

    wconv<<<128, 256, 0, stream>>>(W_in, W_f, Wh);
    gemm_act<__bf16><<<512, 256, 0, stream>>>(inputs, Wh, b_in, b_f, mask, wsx, wsf);
    scan_a<__bf16><<<512, 256, 0, stream>>>(wsx, wsf, Ap, Hp);
    scan_b<<<8, 256, 0, stream>>>(Ap, Hp, Hs);
    scan_c<__bf16><<<512, 256, 0, stream>>>(wsx, wsf, Hs, out);
  }
}

// Round 2
// 151.558 us; speedup vs baseline: 1.1787x; 1.1787x over previous
//
#include <hip/hip_runtime.h>
#include <math.h>

// ---------------------------------------------------------------------------
// EntRNN: x = tanh(inputs @ W_in^T + b_in); f = sigmoid(inputs @ W_f^T + b_f
//          + mask*1e4); h_t = f*x + (1-f)*h_{t-1} scanned over T.
// B=8, T=4096, D_IN=D_OUT=256. Output fp32 (B,T,256).
//
// R2: fused both-matrix MFMA GEMM (A read/convert once), fast exp2-based
//     tanh/sigmoid epilogue, packed {x,f} f16x2 intermediates (halves scan
//     traffic), 3-pass chunked scan.
// ---------------------------------------------------------------------------

typedef _Float16 f16x8 __attribute__((ext_vector_type(8)));
typedef _Float16 f16x4_t __attribute__((ext_vector_type(4)));
typedef float f32x4 __attribute__((ext_vector_type(4)));

constexpr int B_ = 8, T_ = 4096, D_ = 256, K_ = 256;
constexpr int M_ = B_ * T_;          // 32768 rows
constexpr int CHUNK = 64;            // scan chunk length == gemm block rows
constexpr int NCH = T_ / CHUNK;      // 64 chunks per sequence

struct alignas(4) XF { _Float16 x, f; };   // packed activations, 1 dword

__device__ __forceinline__ float fexp2(float a) { return __builtin_amdgcn_exp2f(a); }
__device__ __forceinline__ float frcp(float a) { return __builtin_amdgcn_rcpf(a); }
constexpr float L2E = 1.4426950408889634f;

__device__ __forceinline__ float fast_sigmoid(float z) {
  // 1/(1+e^-z); z->-inf: exp2->inf, rcp(inf)=0 OK
  return frcp(1.f + fexp2(-z * L2E));
}
__device__ __forceinline__ float fast_tanh(float z) {
  // tanh(|z|) = (1-t)/(1+t), t = e^{-2|z|} in (0,1]; then copysign
  const float t = fexp2(-2.f * L2E * fabsf(z));
  const float r = (1.f - t) * frcp(1.f + t);
  return copysignf(r, z);
}

// ---- K0: convert both weight matrices fp32 -> f16, [2][256][256] ----------
__global__ __launch_bounds__(256) void wconv(const float* __restrict__ Win,
                                             const float* __restrict__ Wf,
                                             _Float16* __restrict__ Wh) {
  int i = (blockIdx.x * 256 + threadIdx.x) * 4;   // 128 blocks -> 131072 elems
  const float* src = (i < 65536) ? (Win + i) : (Wf + (i - 65536));
  f32x4 v = *(const f32x4*)src;
  f16x4_t o = { (_Float16)v[0], (_Float16)v[1], (_Float16)v[2], (_Float16)v[3] };
  *(f16x4_t*)(Wh + i) = o;
}

// ---- K1: fused GEMM (both matrices) + activation, packed XF out -----------
// grid = 512 blocks of 64 rows. 4 waves: wave tile 32m x 128n x 2 matrices.
// acc[mat][mt][nt] = 2*2*8 f32x4 = 128 VGPRs. No LDS, no barriers.
__global__ __launch_bounds__(256, 2) void gemm_act(
    const float* __restrict__ A, const _Float16* __restrict__ W,
    const float* __restrict__ bin, const float* __restrict__ bfv,
    const float* __restrict__ mask, XF* __restrict__ xf) {
  const int tid = threadIdx.x;
  const int w = tid >> 6, lane = tid & 63;
  const int quad = lane >> 4, l16 = lane & 15;
  const int mwb = (w >> 1) * 32, nwb = (w & 1) * 128;
  const int row0 = blockIdx.x * 64 + mwb;

  f32x4 acc[2][2][8];
#pragma unroll
  for (int a = 0; a < 2; ++a)
#pragma unroll
    for (int i = 0; i < 2; ++i)
#pragma unroll
      for (int j = 0; j < 8; ++j) acc[a][i][j] = (f32x4){0.f, 0.f, 0.f, 0.f};

  for (int kk = 0; kk < 8; ++kk) {
    const int k0 = kk * 32 + quad * 8;
    f16x8 afr[2];
#pragma unroll
    for (int mt = 0; mt < 2; ++mt) {
      // A fragment: A[m = lane&15][k = quad*8 + j], fp32 -> f16
      const float* p = A + (size_t)(row0 + mt * 16 + l16) * K_ + k0;
      f32x4 lo = *(const f32x4*)p;
      f32x4 hi = *(const f32x4*)(p + 4);
      f16x8 t;
      t[0] = (_Float16)lo[0]; t[1] = (_Float16)lo[1];
      t[2] = (_Float16)lo[2]; t[3] = (_Float16)lo[3];
      t[4] = (_Float16)hi[0]; t[5] = (_Float16)hi[1];
      t[6] = (_Float16)hi[2]; t[7] = (_Float16)hi[3];
      afr[mt] = t;
    }
#pragma unroll
    for (int mat = 0; mat < 2; ++mat) {
      const _Float16* Wp = W + ((size_t)mat << 16);
      f16x8 bfr[8];
#pragma unroll
      for (int nt = 0; nt < 8; ++nt)
        bfr[nt] = *(const f16x8*)(Wp + (size_t)(nwb + nt * 16 + l16) * K_ + k0);
#pragma unroll
      for (int mt = 0; mt < 2; ++mt)
#pragma unroll
        for (int nt = 0; nt < 8; ++nt)
          acc[mat][mt][nt] = __builtin_amdgcn_mfma_f32_16x16x32_f16(
              afr[mt], bfr[nt], acc[mat][mt][nt], 0, 0, 0);
    }
  }

  // epilogue: C/D layout col = lane&15, row = quad*4 + r
  float bx[8], bff[8];
#pragma unroll
  for (int nt = 0; nt < 8; ++nt) {
    const int col = nwb + nt * 16 + l16;
    bx[nt] = bin[col];
    bff[nt] = bfv[col];
  }
#pragma unroll
  for (int mt = 0; mt < 2; ++mt) {
#pragma unroll
    for (int r = 0; r < 4; ++r) {
      const int row = row0 + mt * 16 + quad * 4 + r;
      const float madd = 10000.f * mask[row];
#pragma unroll
      for (int nt = 0; nt < 8; ++nt) {
        const int col = nwb + nt * 16 + l16;
        const float zx = acc[0][mt][nt][r] + bx[nt];
        const float zf = acc[1][mt][nt][r] + bff[nt] + madd;
        XF v;
        v.x = (_Float16)fast_tanh(zx);
        v.f = (_Float16)fast_sigmoid(zf);
        xf[(size_t)row * D_ + col] = v;
      }
    }
  }
}

// ---- K2a: per-chunk summaries (A = prod(1-f), h with h_start = 0) ---------
__global__ __launch_bounds__(256) void scan_a(const XF* __restrict__ xf,
                                              float* __restrict__ Ap,
                                              float* __restrict__ Hp) {
  const int d = threadIdx.x;
  const int g = blockIdx.x;                 // global chunk = b*NCH + c
  const size_t base = (size_t)g * CHUNK * D_ + d;
  float Aacc = 1.f, h = 0.f;
#pragma unroll 8
  for (int i = 0; i < CHUNK; ++i) {
    const XF v = xf[base + (size_t)i * D_];
    const float f = (float)v.f;
    const float a = 1.f - f;
    h = f * (float)v.x + a * h;
    Aacc *= a;
  }
  Ap[(size_t)g * D_ + d] = Aacc;
  Hp[(size_t)g * D_ + d] = h;
}

// ---- K2b: serial combine of 64 chunk summaries per (b,d) ------------------
__global__ __launch_bounds__(256) void scan_b(const float* __restrict__ Ap,
                                              const float* __restrict__ Hp,
                                              float* __restrict__ hs) {
  const int d = threadIdx.x, b = blockIdx.x;
  float h = 0.f;
#pragma unroll 8
  for (int c = 0; c < NCH; ++c) {
    const size_t idx = ((size_t)b * NCH + c) * D_ + d;
    hs[idx] = h;                       // carry INTO chunk c
    h = Hp[idx] + Ap[idx] * h;
  }
}

// ---- K2c: replay chunks with true h_start, write fp32 output --------------
__global__ __launch_bounds__(256) void scan_c(const XF* __restrict__ xf,
                                              const float* __restrict__ hs,
                                              float* __restrict__ out) {
  const int d = threadIdx.x;
  const int g = blockIdx.x;
  float h = hs[(size_t)g * D_ + d];
  const size_t base = (size_t)g * CHUNK * D_ + d;
#pragma unroll 8
  for (int i = 0; i < CHUNK; ++i) {
    const XF v = xf[base + (size_t)i * D_];
    const float f = (float)v.f;
    h = f * (float)v.x + (1.f - f) * h;
    out[base + (size_t)i * D_] = h;
  }
}

// ---------------------------------------------------------------------------
extern "C" void kernel_launch(void* const* d_in, const int* in_sizes, int n_in,
                              void* d_out, int out_size, void* d_ws, size_t ws_size,
                              hipStream_t stream) {
  const float* inputs = (const float*)d_in[0];
  const float* mask   = (const float*)d_in[1];
  const float* W_in   = (const float*)d_in[2];
  const float* b_in   = (const float*)d_in[3];
  const float* W_f    = (const float*)d_in[4];
  const float* b_f    = (const float*)d_in[5];
  float* out = (float*)d_out;
  char* ws = (char*)d_ws;

  constexpr size_t XFSZ = (size_t)M_ * D_ * sizeof(XF);           // 32 MiB
  constexpr size_t WSZ  = (size_t)2 * 256 * 256 * 2;              // 256 KiB
  constexpr size_t SUM  = (size_t)B_ * NCH * D_ * sizeof(float);  // 512 KiB

  XF* xf = (XF*)ws;
  _Float16* Wh = (_Float16*)(ws + XFSZ);
  float* Ap = (float*)(ws + XFSZ + WSZ);
  float* Hp = Ap + SUM / sizeof(float);
  float* Hs = Hp + SUM / sizeof(float);

  wconv<<<128, 256, 0, stream>>>(W_in, W_f, Wh);
  gemm_act<<<512, 256, 0, stream>>>(inputs, Wh, b_in, b_f, mask, xf);
  scan_a<<<512, 256, 0, stream>>>(xf, Ap, Hp);
  scan_b<<<8, 256, 0, stream>>>(Ap, Hp, Hs);
  scan_c<<<512, 256, 0, stream>>>(xf, Hs, out);
}

// Round 4
// 141.296 us; speedup vs baseline: 1.2643x; 1.0726x over previous
//
#include <hip/hip_runtime.h>
#include <math.h>

// ---------------------------------------------------------------------------
// EntRNN R4: LDS-staged fused MFMA GEMM (32x32x16_f16, explicit ds_write
// staging — no global_load_lds after R3 device fault) + activation + fused
// block scan in epilogue; merged combine+replay second kernel.
// B=8, T=4096, D=256. out fp32.
// ---------------------------------------------------------------------------

typedef _Float16 f16x8 __attribute__((ext_vector_type(8)));
typedef float f32x4 __attribute__((ext_vector_type(4)));
typedef float f32x16 __attribute__((ext_vector_type(16)));

constexpr int B_ = 8, T_ = 4096, D_ = 256, K_ = 256;
constexpr int M_ = B_ * T_;          // 32768 rows
constexpr int CHUNK = 64;            // scan chunk == gemm block rows
constexpr int NCH = T_ / CHUNK;      // 64

struct alignas(4) XF { _Float16 x, f; };

__device__ __forceinline__ float fexp2(float a) { return __builtin_amdgcn_exp2f(a); }
__device__ __forceinline__ float frcp(float a) { return __builtin_amdgcn_rcpf(a); }
constexpr float L2E = 1.4426950408889634f;

__device__ __forceinline__ float fast_sigmoid(float z) {
  return frcp(1.f + fexp2(-z * L2E));
}
__device__ __forceinline__ float fast_tanh(float z) {
  const float t = fexp2(-2.f * L2E * fabsf(z));
  return copysignf((1.f - t) * frcp(1.f + t), z);
}

// ---- K0: repack W fp32 -> f16, k-major chunks --------------------------
// Global chunk index g = kk*2048 + (mat*4 + kc)*256 + n ; chunk = 8 f16 =
// W[n][kk*32 + kc*8 .. +8). 16384 chunks, one per thread (grid 64).
__global__ __launch_bounds__(256) void wconv(const float* __restrict__ Win,
                                             const float* __restrict__ Wf,
                                             _Float16* __restrict__ Wh2) {
  const int t = blockIdx.x * 256 + threadIdx.x;
  const int n = t & 255;
  const int kc = (t >> 8) & 3;
  const int mat = (t >> 10) & 1;
  const int kk = t >> 11;
  const float* s = (mat ? Wf : Win) + (size_t)n * K_ + kk * 32 + kc * 8;
  f32x4 a = *(const f32x4*)s;
  f32x4 b = *(const f32x4*)(s + 4);
  f16x8 o;
  o[0] = (_Float16)a[0]; o[1] = (_Float16)a[1];
  o[2] = (_Float16)a[2]; o[3] = (_Float16)a[3];
  o[4] = (_Float16)b[0]; o[5] = (_Float16)b[1];
  o[6] = (_Float16)b[2]; o[7] = (_Float16)b[3];
  *(f16x8*)(Wh2 + (size_t)t * 8) = o;
}

// ---- K1: LDS-staged GEMM + activations + fused chunk scan -----------------
// grid 512 x 256 thr (4 waves: mw = w>>1 -> 32-row half, nw = w&1 -> 128-col
// half). Per kk (K-slice 32):
//   ldsA 4 KiB : [m(64)][pc(4)] chunks of 8 f16, pc = (kc + m) & 3
//   ldsW 32 KiB: [mat(2)][kc(4)][n(256)] chunks of 8 f16 (linear copy)
// Epilogue: XF -> smem[64][256] (64 KiB union) + global; block scan -> Ap/Hp.
__global__ __launch_bounds__(256) void gemm_fused(
    const float* __restrict__ A, const _Float16* __restrict__ Wh2,
    const float* __restrict__ bin, const float* __restrict__ bfv,
    const float* __restrict__ mask, XF* __restrict__ xf,
    float* __restrict__ Ap, float* __restrict__ Hp) {
  __shared__ __align__(16) char smem[65536];
  char* ldsA = smem;
  char* ldsW = smem + 4096;

  const int tid = threadIdx.x;
  const int w = tid >> 6, lane = tid & 63;
  const int mw = w >> 1, nw = w & 1;
  const int nl = lane & 31, kh = lane >> 5;
  const int ml = mw * 32 + nl;
  const int row0b = blockIdx.x * 64;

  f32x16 acc[2][4];
#pragma unroll
  for (int mat = 0; mat < 2; ++mat)
#pragma unroll
    for (int nt = 0; nt < 4; ++nt) acc[mat][nt] = (f32x16)(0.f);

  // A staging: one 16B chunk per thread per kk (256 chunks total)
  const int am = tid >> 2, apc = tid & 3, akc = (apc - am) & 3;
  const float* agp = A + (size_t)(row0b + am) * K_ + akc * 8;
  char* const alds = ldsA + tid * 16;

  for (int kk = 0; kk < 8; ++kk) {
    {  // stage A: load 8 fp32, convert, one ds_write_b128
      const float* p = agp + kk * 32;
      f32x4 lo = *(const f32x4*)p;
      f32x4 hi = *(const f32x4*)(p + 4);
      f16x8 t;
      t[0] = (_Float16)lo[0]; t[1] = (_Float16)lo[1];
      t[2] = (_Float16)lo[2]; t[3] = (_Float16)lo[3];
      t[4] = (_Float16)hi[0]; t[5] = (_Float16)hi[1];
      t[6] = (_Float16)hi[2]; t[7] = (_Float16)hi[3];
      *(f16x8*)alds = t;
    }
    // stage W: 2048 chunks, 8 per thread, straight copy (pre-repacked)
#pragma unroll
    for (int j = 0; j < 8; ++j) {
      const int c = j * 256 + tid;
      f16x8 v = *(const f16x8*)(Wh2 + (size_t)kk * 16384 + (size_t)c * 8);
      *(f16x8*)(ldsW + (size_t)c * 16) = v;
    }
    __syncthreads();

    // A fragments: A[m = lane&31][k = kh*8 + j + i2*16]
    f16x8 afr[2];
#pragma unroll
    for (int i2 = 0; i2 < 2; ++i2) {
      const int kc = i2 * 2 + kh;
      const int pc = (kc + ml) & 3;
      afr[i2] = *(const f16x8*)(ldsA + (ml * 4 + pc) * 16);
    }
    // B fragments + MFMA
#pragma unroll
    for (int mat = 0; mat < 2; ++mat)
#pragma unroll
      for (int nt = 0; nt < 4; ++nt) {
        const int n = nw * 128 + nt * 32 + nl;
#pragma unroll
        for (int i2 = 0; i2 < 2; ++i2) {
          const int kc = i2 * 2 + kh;
          f16x8 bfr = *(const f16x8*)(ldsW + ((mat * 4 + kc) * 256 + n) * 16);
          acc[mat][nt] = __builtin_amdgcn_mfma_f32_32x32x16_f16(
              afr[i2], bfr, acc[mat][nt], 0, 0, 0);
        }
      }
    __syncthreads();
  }

  // ---- epilogue: bias + mask + activations; write LDS + global ----
  float bx[4], bf[4];
#pragma unroll
  for (int nt = 0; nt < 4; ++nt) {
    const int col = nw * 128 + nt * 32 + nl;
    bx[nt] = bin[col];
    bf[nt] = bfv[col];
  }
  float madd[16];
  int rowl[16];
#pragma unroll
  for (int reg = 0; reg < 16; ++reg) {
    const int rl = mw * 32 + (reg & 3) + 8 * (reg >> 2) + 4 * kh;
    rowl[reg] = rl;
    madd[reg] = 10000.f * mask[row0b + rl];
  }
#pragma unroll
  for (int nt = 0; nt < 4; ++nt) {
    const int col = nw * 128 + nt * 32 + nl;
#pragma unroll
    for (int reg = 0; reg < 16; ++reg) {
      const float zx = acc[0][nt][reg] + bx[nt];
      const float zf = acc[1][nt][reg] + bf[nt] + madd[reg];
      XF v;
      v.x = (_Float16)fast_tanh(zx);
      v.f = (_Float16)fast_sigmoid(zf);
      *(XF*)(smem + ((size_t)rowl[reg] * D_ + col) * 4) = v;
      xf[((size_t)row0b + rowl[reg]) * D_ + col] = v;
    }
  }
  __syncthreads();

  // ---- fused chunk scan: thread d scans 64 t from LDS ----
  const int d = tid;
  float Aa = 1.f, h = 0.f;
#pragma unroll 8
  for (int t = 0; t < CHUNK; ++t) {
    const XF v = *(const XF*)(smem + ((size_t)t * D_ + d) * 4);
    const float f = (float)v.f;
    const float a = 1.f - f;
    h = f * (float)v.x + a * h;
    Aa *= a;
  }
  Ap[(size_t)blockIdx.x * D_ + d] = Aa;
  Hp[(size_t)blockIdx.x * D_ + d] = h;
}

// ---- K2: combine predecessor summaries + replay chunk, write fp32 out -----
__global__ __launch_bounds__(256) void scan_final(const XF* __restrict__ xf,
                                                  const float* __restrict__ Ap,
                                                  const float* __restrict__ Hp,
                                                  float* __restrict__ out) {
  const int g = blockIdx.x;
  const int b = g >> 6, c = g & 63;
  const int d = threadIdx.x;
  const float* ap = Ap + ((size_t)b * NCH) * D_ + d;
  const float* hp = Hp + ((size_t)b * NCH) * D_ + d;
  float h = 0.f;
  for (int j = 0; j < c; ++j) h = hp[(size_t)j * D_] + ap[(size_t)j * D_] * h;

  const size_t base = (size_t)g * CHUNK * D_ + d;
#pragma unroll 8
  for (int t = 0; t < CHUNK; ++t) {
    const XF v = xf[base + (size_t)t * D_];
    const float f = (float)v.f;
    h = f * (float)v.x + (1.f - f) * h;
    out[base + (size_t)t * D_] = h;
  }
}

// ---------------------------------------------------------------------------
extern "C" void kernel_launch(void* const* d_in, const int* in_sizes, int n_in,
                              void* d_out, int out_size, void* d_ws, size_t ws_size,
                              hipStream_t stream) {
  const float* inputs = (const float*)d_in[0];
  const float* mask   = (const float*)d_in[1];
  const float* W_in   = (const float*)d_in[2];
  const float* b_in   = (const float*)d_in[3];
  const float* W_f    = (const float*)d_in[4];
  const float* b_f    = (const float*)d_in[5];
  float* out = (float*)d_out;
  char* ws = (char*)d_ws;

  constexpr size_t XFSZ = (size_t)M_ * D_ * sizeof(XF);           // 32 MiB
  constexpr size_t WSZ  = (size_t)2 * 256 * 256 * 2;              // 256 KiB
  constexpr size_t SUM  = (size_t)B_ * NCH * D_ * sizeof(float);  // 512 KiB

  XF* xf = (XF*)ws;
  _Float16* Wh2 = (_Float16*)(ws + XFSZ);
  float* Ap = (float*)(ws + XFSZ + WSZ);
  float* Hp = Ap + SUM / sizeof(float);

  wconv<<<64, 256, 0, stream>>>(W_in, W_f, Wh2);
  gemm_fused<<<512, 256, 0, stream>>>(inputs, Wh2, b_in, b_f, mask, xf, Ap, Hp);
  scan_final<<<512, 256, 0, stream>>>(xf, Ap, Hp, out);
}

// Round 6
// 129.884 us; speedup vs baseline: 1.3754x; 1.0879x over previous
//
#include <hip/hip_runtime.h>
#include <math.h>

// ---------------------------------------------------------------------------
// EntRNN R6: two-kernel structure (R4, known-good) + R5's K-loop upgrades:
// A staged to LDS once (f16, xor-swizzle), W k-slices register-pipelined.
// gemm_fused: MFMA 32x32x16_f16 + activation + fused block scan -> xf,Ap,Hp.
// scan_final: fold predecessor summaries + replay -> fp32 out.
// B=8, T=4096, D=256.
// ---------------------------------------------------------------------------

typedef _Float16 f16x8 __attribute__((ext_vector_type(8)));
typedef float f32x4 __attribute__((ext_vector_type(4)));
typedef float f32x16 __attribute__((ext_vector_type(16)));

constexpr int B_ = 8, T_ = 4096, D_ = 256, K_ = 256;
constexpr int M_ = B_ * T_;          // 32768 rows
constexpr int CHUNK = 64;            // rows per block == scan chunk
constexpr int NCH = T_ / CHUNK;      // 64 chunks per sequence

struct alignas(4) XF { _Float16 x, f; };

__device__ __forceinline__ float fexp2(float a) { return __builtin_amdgcn_exp2f(a); }
__device__ __forceinline__ float frcp(float a) { return __builtin_amdgcn_rcpf(a); }
constexpr float L2E = 1.4426950408889634f;

__device__ __forceinline__ float fast_sigmoid(float z) {
  return frcp(1.f + fexp2(-z * L2E));
}
__device__ __forceinline__ float fast_tanh(float z) {
  const float t = fexp2(-2.f * L2E * fabsf(z));
  return copysignf((1.f - t) * frcp(1.f + t), z);
}

// ---- K0: repack W fp32 -> f16, k-major chunks: g = kk*2048+(mat*4+kc)*256+n
__global__ __launch_bounds__(256) void wconv(const float* __restrict__ Win,
                                             const float* __restrict__ Wf,
                                             _Float16* __restrict__ Wh2) {
  const int t = blockIdx.x * 256 + threadIdx.x;
  const int n = t & 255;
  const int kc = (t >> 8) & 3;
  const int mat = (t >> 10) & 1;
  const int kk = t >> 11;
  const float* s = (mat ? Wf : Win) + (size_t)n * K_ + kk * 32 + kc * 8;
  f32x4 a = *(const f32x4*)s;
  f32x4 b = *(const f32x4*)(s + 4);
  f16x8 o;
  o[0] = (_Float16)a[0]; o[1] = (_Float16)a[1];
  o[2] = (_Float16)a[2]; o[3] = (_Float16)a[3];
  o[4] = (_Float16)b[0]; o[5] = (_Float16)b[1];
  o[6] = (_Float16)b[2]; o[7] = (_Float16)b[3];
  *(f16x8*)(Wh2 + (size_t)t * 8) = o;
}

// ---- K1: GEMM + activations + fused chunk scan ----------------------------
// 512 blocks x 256 thr. 4 waves: mw=w>>1 (32-row half), nw=w&1 (128-col
// half). LDS 64 KiB: [A 32K | W-slice 32K] in K-loop, XF[64][256] after.
__global__ __launch_bounds__(256, 2) void gemm_fused(
    const float* __restrict__ A, const _Float16* __restrict__ Wh2,
    const float* __restrict__ bin, const float* __restrict__ bfv,
    const float* __restrict__ mask, XF* __restrict__ xf,
    float* __restrict__ Ap, float* __restrict__ Hp) {
  __shared__ __align__(16) char smem[65536];
  char* ldsA = smem;            // [m(64)][swz(32)] 16B chunks, swz = kcg ^ (m&31)
  char* ldsW = smem + 32768;    // per-kk slice: [(mat*4+kc)*256 + n] 16B chunks

  const int tid = threadIdx.x;
  const int w = tid >> 6, lane = tid & 63;
  const int mw = w >> 1, nw = w & 1;
  const int nl = lane & 31, kh = lane >> 5;
  const int ml = mw * 32 + nl;
  const int g = blockIdx.x;
  const int row0b = g * CHUNK;

  f32x16 acc[2][4];
#pragma unroll
  for (int mat = 0; mat < 2; ++mat)
#pragma unroll
    for (int nt = 0; nt < 4; ++nt) acc[mat][nt] = (f32x16)(0.f);

  // ---- stage ALL of A (64 rows x 256 k) fp32->f16, xor-swizzled ----
  {
    const int am = tid >> 2;               // row 0..63
    const int ak4 = (tid & 3) * 8;         // base k-chunk (8 f16 per chunk)
    const float* agp = A + (size_t)(row0b + am) * K_ + ak4 * 8;
#pragma unroll
    for (int j = 0; j < 8; ++j) {
      const int kcg = ak4 + j;
      f32x4 lo = *(const f32x4*)(agp + j * 8);
      f32x4 hi = *(const f32x4*)(agp + j * 8 + 4);
      f16x8 t;
      t[0] = (_Float16)lo[0]; t[1] = (_Float16)lo[1];
      t[2] = (_Float16)lo[2]; t[3] = (_Float16)lo[3];
      t[4] = (_Float16)hi[0]; t[5] = (_Float16)hi[1];
      t[6] = (_Float16)hi[2]; t[7] = (_Float16)hi[3];
      *(f16x8*)(ldsA + am * 512 + ((kcg ^ (am & 31)) << 4)) = t;
    }
  }

  // ---- prologue: W slice kk=0 into regs ----
  f16x8 wreg[8];
#pragma unroll
  for (int j = 0; j < 8; ++j)
    wreg[j] = *(const f16x8*)(Wh2 + (size_t)(j * 256 + tid) * 8);

  // ---- K-loop: write slice | barrier | prefetch kk+1 | frags+MFMA | barrier
  for (int kk = 0; kk < 8; ++kk) {
#pragma unroll
    for (int j = 0; j < 8; ++j)
      *(f16x8*)(ldsW + (size_t)(j * 256 + tid) * 16) = wreg[j];
    __syncthreads();                      // slice (and, first iter, A) ready
    if (kk < 7) {
#pragma unroll
      for (int j = 0; j < 8; ++j)
        wreg[j] = *(const f16x8*)(Wh2 + (size_t)(kk + 1) * 16384 +
                                  (size_t)(j * 256 + tid) * 8);
    }
    f16x8 afr[2];
#pragma unroll
    for (int i2 = 0; i2 < 2; ++i2) {
      const int kcg = kk * 4 + i2 * 2 + kh;
      afr[i2] = *(const f16x8*)(ldsA + ml * 512 + ((kcg ^ (ml & 31)) << 4));
    }
#pragma unroll
    for (int mat = 0; mat < 2; ++mat)
#pragma unroll
      for (int nt = 0; nt < 4; ++nt) {
        const int n = nw * 128 + nt * 32 + nl;
#pragma unroll
        for (int i2 = 0; i2 < 2; ++i2) {
          const int kc = i2 * 2 + kh;
          f16x8 bfr = *(const f16x8*)(ldsW + (size_t)((mat * 4 + kc) * 256 + n) * 16);
          acc[mat][nt] = __builtin_amdgcn_mfma_f32_32x32x16_f16(
              afr[i2], bfr, acc[mat][nt], 0, 0, 0);
        }
      }
    __syncthreads();                      // slice consumed (next write / XF safe)
  }

  // ---- epilogue: bias + mask + activations -> XF in LDS + global ----
  float bx[4], bf[4];
#pragma unroll
  for (int nt = 0; nt < 4; ++nt) {
    const int col = nw * 128 + nt * 32 + nl;
    bx[nt] = bin[col];
    bf[nt] = bfv[col];
  }
  float madd[16];
  int rowl[16];
#pragma unroll
  for (int reg = 0; reg < 16; ++reg) {
    const int rl = mw * 32 + (reg & 3) + 8 * (reg >> 2) + 4 * kh;
    rowl[reg] = rl;
    madd[reg] = 10000.f * mask[row0b + rl];
  }
#pragma unroll
  for (int nt = 0; nt < 4; ++nt) {
    const int col = nw * 128 + nt * 32 + nl;
#pragma unroll
    for (int reg = 0; reg < 16; ++reg) {
      const float zx = acc[0][nt][reg] + bx[nt];
      const float zf = acc[1][nt][reg] + bf[nt] + madd[reg];
      XF v;
      v.x = (_Float16)fast_tanh(zx);
      v.f = (_Float16)fast_sigmoid(zf);
      *(XF*)(smem + ((size_t)rowl[reg] * D_ + col) * 4) = v;
      xf[((size_t)row0b + rowl[reg]) * D_ + col] = v;
    }
  }
  __syncthreads();

  // ---- fused chunk scan: thread d scans 64 t from LDS ----
  const int d = tid;
  float Aa = 1.f, h = 0.f;
#pragma unroll 8
  for (int t = 0; t < CHUNK; ++t) {
    const XF v = *(const XF*)(smem + ((size_t)t * D_ + d) * 4);
    const float f = (float)v.f;
    const float a = 1.f - f;
    h = f * (float)v.x + a * h;
    Aa *= a;
  }
  Ap[(size_t)g * D_ + d] = Aa;
  Hp[(size_t)g * D_ + d] = h;
}

// ---- K2: combine predecessor summaries + replay chunk, write fp32 out -----
__global__ __launch_bounds__(256) void scan_final(const XF* __restrict__ xf,
                                                  const float* __restrict__ Ap,
                                                  const float* __restrict__ Hp,
                                                  float* __restrict__ out) {
  const int g = blockIdx.x;
  const int b = g >> 6, c = g & 63;
  const int d = threadIdx.x;
  const float* ap = Ap + ((size_t)b * NCH) * D_ + d;
  const float* hp = Hp + ((size_t)b * NCH) * D_ + d;
  float h = 0.f;
  for (int j = 0; j < c; ++j) h = hp[(size_t)j * D_] + ap[(size_t)j * D_] * h;

  const size_t base = (size_t)g * CHUNK * D_ + d;
#pragma unroll 8
  for (int t = 0; t < CHUNK; ++t) {
    const XF v = xf[base + (size_t)t * D_];
    const float f = (float)v.f;
    h = f * (float)v.x + (1.f - f) * h;
    out[base + (size_t)t * D_] = h;
  }
}

// ---------------------------------------------------------------------------
extern "C" void kernel_launch(void* const* d_in, const int* in_sizes, int n_in,
                              void* d_out, int out_size, void* d_ws, size_t ws_size,
                              hipStream_t stream) {
  const float* inputs = (const float*)d_in[0];
  const float* mask   = (const float*)d_in[1];
  const float* W_in   = (const float*)d_in[2];
  const float* b_in   = (const float*)d_in[3];
  const float* W_f    = (const float*)d_in[4];
  const float* b_f    = (const float*)d_in[5];
  float* out = (float*)d_out;
  char* ws = (char*)d_ws;

  constexpr size_t XFSZ = (size_t)M_ * D_ * sizeof(XF);           // 32 MiB
  constexpr size_t WSZ  = (size_t)2 * 256 * 256 * 2;              // 256 KiB
  constexpr size_t SUM  = (size_t)M_ / CHUNK * D_ * sizeof(float); // 512 KiB

  XF* xf = (XF*)ws;
  _Float16* Wh2 = (_Float16*)(ws + XFSZ);
  float* Ap = (float*)(ws + XFSZ + WSZ);
  float* Hp = Ap + SUM / sizeof(float);

  wconv<<<64, 256, 0, stream>>>(W_in, W_f, Wh2);
  gemm_fused<<<512, 256, 0, stream>>>(inputs, Wh2, b_in, b_f, mask, xf, Ap, Hp);
  scan_final<<<512, 256, 0, stream>>>(xf, Ap, Hp, out);
}